// Round 16
// baseline (400.814 us; speedup 1.0000x reference)
//
#include <hip/hip_runtime.h>
#include <cstdint>

// MSCN forward, round 16: occupancy experiment on enc (the one untested axis).
//  k_enc_all: 512-thr blocks (8 waves), 128-row tiles, ONE 16-row group per
//  wave (halves per-wave A-state), DIRECT B loads (no bcur/bnxt pipeline ->
//  ~-40 VGPR). Same tile bytes, same reduce & atomic volume as R10.
//  Tail identical to R15 (== R10 measured).
//  7 dispatches: memset(sm) | count+zero | scan | fill+prepw | enc | bnstats | head

constexpr int P_N = 20000;
constexpr int HD  = 128;

typedef __attribute__((ext_vector_type(8))) short  short8v;
typedef __attribute__((ext_vector_type(4))) float  float4v;
typedef __attribute__((ext_vector_type(8))) float  float8v;
typedef __attribute__((ext_vector_type(8))) __bf16 bf16x8;

__device__ inline ushort f2bf(float f) {                       // RNE f32->bf16
    uint32_t u = __builtin_bit_cast(uint32_t, f);
    u += 0x7fffu + ((u >> 16) & 1u);
    return (ushort)(u >> 16);
}
__device__ inline short8v cvt8v(float4 a, float4 b) {          // v_cvt_pk_bf16
    float8v f = {a.x, a.y, a.z, a.w, b.x, b.y, b.z, b.w};
    bf16x8 h = __builtin_convertvector(f, bf16x8);
    return __builtin_bit_cast(short8v, h);
}
__device__ inline float4v mfma16(short8v a, short8v b, float4v c) {
    return __builtin_amdgcn_mfma_f32_16x16x32_bf16(a, b, c, 0, 0, 0);
}

// ---------------- histogram over all 4 types + x-zero fold ----------------
__global__ void k_count_zero(const int* __restrict__ i0, const int* __restrict__ i1,
                             const int* __restrict__ i2, const int* __restrict__ i3,
                             int n0, int n1, int n2, int n3, int* __restrict__ counts,
                             int nb_count, float4* __restrict__ xz) {
    if (blockIdx.x < (unsigned)nb_count) {
        int i = blockIdx.x * blockDim.x + threadIdx.x;
        const int n01 = n0 + n1, n012 = n0 + n1 + n2, tot = n012 + n3;
        if (i >= tot) return;
        int tp, li; const int* p;
        if (i < n0)        { tp = 0; li = i;        p = i0; }
        else if (i < n01)  { tp = 1; li = i - n0;   p = i1; }
        else if (i < n012) { tp = 2; li = i - n01;  p = i2; }
        else               { tp = 3; li = i - n012; p = i3; }
        atomicAdd(&counts[tp * P_N + p[li]], 1);
    } else {
        const int NZ = P_N * 128;
        int i = (blockIdx.x - nb_count) * blockDim.x + threadIdx.x;
        const int stride = 2048 * 256;
        const float4 z = {0.f, 0.f, 0.f, 0.f};
        for (; i < NZ; i += stride) xz[i] = z;
    }
}

// ---------------- scan -> curs + invc + 160-entry list/splan pads ----------
__global__ void k_scan(int* __restrict__ counts_all, int* __restrict__ cur_all,
                       float* __restrict__ invc,
                       int* l0, int* l1, int* l2, int* l3,
                       int* s0, int* s1, int* s2, int* s3,
                       int n0, int n1, int n2, int n3) {
    const int type = blockIdx.x;
    int* counts = counts_all + type * P_N;
    int* curs   = cur_all   + type * P_N;
    float* ic   = invc      + type * P_N;
    const int T = 256;
    const int CH = (P_N + T - 1) / T;
    int t = threadIdx.x;
    __shared__ int sums[T];
    __shared__ int pref[T];
    int local = 0;
    int p0 = t * CH;
    for (int i = 0; i < CH; ++i) {
        int p = p0 + i;
        if (p < P_N) local += counts[p];
    }
    sums[t] = local;
    __syncthreads();
    if (t == 0) {
        int run = 0;
        for (int j = 0; j < T; ++j) { pref[j] = run; run += sums[j]; }
    }
    __syncthreads();
    int run = pref[t];
    for (int i = 0; i < CH; ++i) {
        int p = p0 + i;
        if (p < P_N) {
            int c = counts[p];
            curs[p] = run; run += c;
            ic[p] = 1.f / (float)max(c, 1);
        }
    }
    int N; int *lp, *sp;
    if (type == 0)      { N = n0; lp = l0; sp = s0; }
    else if (type == 1) { N = n1; lp = l1; sp = s1; }
    else if (type == 2) { N = n2; lp = l2; sp = s2; }
    else                { N = n3; lp = l3; sp = s3; }
    if (t < 160) { lp[N + t] = 0; sp[N + t] = -1; }
}

// ---------------- CSR fill + weight prep, one dispatch (block split) -------
__global__ void k_fill_prepw(const int* __restrict__ i0, const int* __restrict__ i1,
                             const int* __restrict__ i2, const int* __restrict__ i3,
                             int n0, int n1, int n2, int n3, int* __restrict__ cur_all,
                             int* l0, int* l1, int* l2, int* l3,
                             int* s0p, int* s1p, int* s2p, int* s3p,
                             int nb_fill,
                             const float* w0s, const float* w1s, const float* w2s,
                             const float* w3s, const float* w4s, const float* w5s,
                             ushort* d0, ushort* d1, ushort* d2, ushort* d3,
                             ushort* d4, ushort* d5) {
    if (blockIdx.x < (unsigned)nb_fill) {
        int i = blockIdx.x * blockDim.x + threadIdx.x;
        const int n01 = n0 + n1, n012 = n0 + n1 + n2, tot = n012 + n3;
        if (i >= tot) return;
        int tp, li; const int* p; int *lst, *spl;
        if (i < n0)        { tp = 0; li = i;        p = i0; lst = l0; spl = s0p; }
        else if (i < n01)  { tp = 1; li = i - n0;   p = i1; lst = l1; spl = s1p; }
        else if (i < n012) { tp = 2; li = i - n01;  p = i2; lst = l2; spl = s2p; }
        else               { tp = 3; li = i - n012; p = i3; lst = l3; spl = s3p; }
        int pl = p[li];
        int pos = atomicAdd(&cur_all[tp * P_N + pl], 1);
        lst[pos] = li;
        spl[pos] = pl;
    } else {
        int i = (blockIdx.x - nb_fill) * blockDim.x + threadIdx.x;
        const float* s; ushort* d; int Dv, li;
        if (i < 12288)       { s = w0s; d = d0; Dv = 96;  li = i; }
        else if (i < 32768)  { s = w1s; d = d1; Dv = 160; li = i - 12288; }
        else if (i < 40960)  { s = w2s; d = d2; Dv = 64;  li = i - 32768; }
        else if (i < 49152)  { s = w3s; d = d3; Dv = 64;  li = i - 40960; }
        else if (i < 114688) { s = w4s; d = d4; Dv = 512; li = i - 49152; }
        else if (i < 131072) { s = w5s; d = d5; Dv = 128; li = i - 114688; }
        else return;
        int n = li / Dv, k = li - n * Dv;
        d[li] = f2bf(s[k * HD + n]);
    }
}

// ---------------- segment reduce over one 64-row group (t<256) -------------
__device__ __forceinline__ void reduce_group(float (*Cs)[132], const int* plans,
                                             float* __restrict__ x, int toff, int pbase) {
    const int t = threadIdx.x;
    if (t >= 256) return;
    const int col = t & 127, half = t >> 7;
    int curp = -2; float s = 0.f;
    #pragma unroll 8
    for (int r = 0; r < 32; ++r) {
        int p = plans[pbase + half * 32 + r];        // wave-uniform
        float v = Cs[half * 32 + r][col];
        if (p != curp) {
            if (curp >= 0) atomicAdd(&x[(size_t)curp * 512 + toff + col], s);
            s = 0.f; curp = p;
        }
        if (p >= 0) s += v;
    }
    if (curp >= 0) atomicAdd(&x[(size_t)curp * 512 + toff + col], s);
}

// ---------------- encoder body: 128-row tile, 8 waves x one 16-row group ----
template<int D>
__device__ __forceinline__ void enc_body(
    const float* __restrict__ feat, const ushort* __restrict__ WT,
    const float* __restrict__ bias, const int* __restrict__ list,
    const int* __restrict__ splan, float* __restrict__ x, int toff, int tile,
    float (*Cs)[132], int* plans)
{
    constexpr int NKS = D / 32;
    const int t = threadIdx.x;
    const int w = t >> 6, lane = t & 63;
    const int lq = lane >> 4, lr = lane & 15;
    const int m0 = tile * 128;

    if (t < 128) plans[t] = splan[m0 + t];
    const int lv = list[m0 + w * 16 + lr];
    const float* ap = feat + (size_t)lv * D + lq * 8;

    // stage this wave's gathers (one vmcnt batch), convert
    float4 st[2 * NKS];
    #pragma unroll
    for (int ks = 0; ks < NKS; ++ks) {
        st[2 * ks]     = *(const float4*)(ap + ks * 32);
        st[2 * ks + 1] = *(const float4*)(ap + ks * 32 + 4);
    }
    short8v a[NKS];
    #pragma unroll
    for (int ks = 0; ks < NKS; ++ks) a[ks] = cvt8v(st[2 * ks], st[2 * ks + 1]);

    float bv[8];
    #pragma unroll
    for (int nf = 0; nf < 8; ++nf) bv[nf] = bias[nf * 16 + lr];

    float4v acc[8];
    #pragma unroll
    for (int nf = 0; nf < 8; ++nf) acc[nf] = (float4v){0.f, 0.f, 0.f, 0.f};

    // direct B loads (L1/L2-served; whole grid shares <=40KB)
    const ushort* wp = WT + lr * D + lq * 8;
    #pragma unroll
    for (int ks = 0; ks < NKS; ++ks) {
        #pragma unroll
        for (int nf = 0; nf < 8; ++nf) {
            short8v b = *(const short8v*)(wp + nf * 16 * D + ks * 32);
            acc[nf] = mfma16(a[ks], b, acc[nf]);
        }
    }

    // pass 1: waves 0-3 dump rows 0-63; reduce; pass 2: waves 4-7 rows 64-127
    if (w < 4) {
        #pragma unroll
        for (int nf = 0; nf < 8; ++nf) {
            #pragma unroll
            for (int j = 0; j < 4; ++j)
                Cs[w * 16 + lq * 4 + j][nf * 16 + lr] = fmaxf(acc[nf][j] + bv[nf], 0.f);
        }
    }
    __syncthreads();
    reduce_group(Cs, plans, x, toff, 0);
    __syncthreads();
    if (w >= 4) {
        #pragma unroll
        for (int nf = 0; nf < 8; ++nf) {
            #pragma unroll
            for (int j = 0; j < 4; ++j)
                Cs[(w - 4) * 16 + lq * 4 + j][nf * 16 + lr] = fmaxf(acc[nf][j] + bv[nf], 0.f);
        }
    }
    __syncthreads();
    reduce_group(Cs, plans, x, toff, 64);
}

__global__ __launch_bounds__(512, 2) void k_enc_all(
    const float* f0, const float* f1, const float* f2, const float* f3,
    const ushort* w0, const ushort* w1, const ushort* w2, const ushort* w3,
    const float* b0, const float* b1, const float* b2, const float* b3,
    const int* l0, const int* l1, const int* l2, const int* l3,
    const int* s0, const int* s1, const int* s2, const int* s3,
    float* x, int ntp, int ntt, int nta)
{
    __shared__ float Cs[64][132];
    __shared__ int plans[128];
    int bid = blockIdx.x;
    if (bid < ntp) { enc_body<160>(f1, w1, b1, l1, s1, x, 128, bid, Cs, plans); return; }
    bid -= ntp;
    if (bid < ntt) { enc_body<96>(f0, w0, b0, l0, s0, x, 0, bid, Cs, plans); return; }
    bid -= ntt;
    if (bid < nta) { enc_body<64>(f2, w2, b2, l2, s2, x, 256, bid, Cs, plans); return; }
    bid -= nta;
    enc_body<64>(f3, w3, b3, l3, s3, x, 384, bid, Cs, plans);
}

// ---------------- BN stats + fused finalize (last block) -------------------
__global__ __launch_bounds__(512) void k_bnstats(
    const float* __restrict__ x, const float* __restrict__ invc,
    float* __restrict__ bnsum, int* __restrict__ done,
    const float* __restrict__ gamma, const float* __restrict__ beta,
    float* __restrict__ scale, float* __restrict__ shiftv)
{
    const int t = threadIdx.x;
    const int r0 = blockIdx.x * 40;
    const int r1 = min(r0 + 40, P_N);
    const float* ic = invc + (t >> 7) * P_N;
    float s = 0.f, q = 0.f;
    for (int r = r0; r < r1; ++r) {
        float v = x[(size_t)r * 512 + t] * ic[r];
        s += v; q += v * v;
    }
    atomicAdd(&bnsum[t], s);
    atomicAdd(&bnsum[512 + t], q);

    __shared__ int amLast;
    __syncthreads();
    if (t == 0) {
        __threadfence();
        int prev = __hip_atomic_fetch_add(done, 1, __ATOMIC_ACQ_REL, __HIP_MEMORY_SCOPE_AGENT);
        amLast = (prev == (int)gridDim.x - 1);
    }
    __syncthreads();
    if (amLast) {
        const float invn = 1.f / (float)P_N;
        float sm = __hip_atomic_load(&bnsum[t],       __ATOMIC_RELAXED, __HIP_MEMORY_SCOPE_AGENT);
        float sq = __hip_atomic_load(&bnsum[512 + t], __ATOMIC_RELAXED, __HIP_MEMORY_SCOPE_AGENT);
        float mu  = sm * invn;
        float var = sq * invn - mu * mu;
        float rstd = rsqrtf(fmaxf(var, 0.f) + 1e-5f);
        float sc = gamma[t] * rstd;
        scale[t]  = sc;
        shiftv[t] = beta[t] - mu * sc;
    }
}

// ---------------- fused MFMA head: 16 plans/block, 1250 blocks -------------
__global__ __launch_bounds__(256) void k_head(
    const float* __restrict__ x, const float* __restrict__ invc,
    const float* __restrict__ scale, const float* __restrict__ shiftv,
    const ushort* __restrict__ WT1, const float* __restrict__ b1,
    const ushort* __restrict__ WT2, const float* __restrict__ b2,
    const float* __restrict__ W3, const float* __restrict__ b3,
    float* __restrict__ out)
{
    __shared__ float h[16][132];
    __shared__ float red[4][16];
    const int t = threadIdx.x;
    const int w = t >> 6, lane = t & 63;
    const int lq = lane >> 4, lr = lane & 15;
    const int p0 = blockIdx.x * 16;
    const int row = p0 + lr;
    const float* xr = x + (size_t)row * 512;

    float4v acc[2];
    #pragma unroll
    for (int nf = 0; nf < 2; ++nf) acc[nf] = (float4v){0.f, 0.f, 0.f, 0.f};

    #pragma unroll
    for (int kc = 0; kc < 4; ++kc) {
        const float ic = invc[kc * P_N + row];
        float4 st[8];
        #pragma unroll
        for (int k2 = 0; k2 < 4; ++k2) {
            const int k0 = kc * 128 + k2 * 32 + lq * 8;
            st[2 * k2]     = *(const float4*)(xr + k0);
            st[2 * k2 + 1] = *(const float4*)(xr + k0 + 4);
        }
        short8v a[4];
        #pragma unroll
        for (int k2 = 0; k2 < 4; ++k2) {
            const int k0 = kc * 128 + k2 * 32 + lq * 8;
            float4 sc0 = *(const float4*)(scale + k0);
            float4 sc1 = *(const float4*)(scale + k0 + 4);
            float4 sh0 = *(const float4*)(shiftv + k0);
            float4 sh1 = *(const float4*)(shiftv + k0 + 4);
            float4 v0, v1;
            v0.x = st[2*k2].x   * ic * sc0.x + sh0.x;
            v0.y = st[2*k2].y   * ic * sc0.y + sh0.y;
            v0.z = st[2*k2].z   * ic * sc0.z + sh0.z;
            v0.w = st[2*k2].w   * ic * sc0.w + sh0.w;
            v1.x = st[2*k2+1].x * ic * sc1.x + sh1.x;
            v1.y = st[2*k2+1].y * ic * sc1.y + sh1.y;
            v1.z = st[2*k2+1].z * ic * sc1.z + sh1.z;
            v1.w = st[2*k2+1].w * ic * sc1.w + sh1.w;
            a[k2] = cvt8v(v0, v1);
        }
        #pragma unroll
        for (int k2 = 0; k2 < 4; ++k2) {
            const int ks = kc * 4 + k2;
            #pragma unroll
            for (int nf = 0; nf < 2; ++nf) {
                short8v b = *(const short8v*)(WT1 + (size_t)(w * 32 + nf * 16 + lr) * 512 + ks * 32 + lq * 8);
                acc[nf] = mfma16(a[k2], b, acc[nf]);
            }
        }
    }
    #pragma unroll
    for (int nf = 0; nf < 2; ++nf) {
        const int c = w * 32 + nf * 16 + lr;
        const float bvv = b1[c];
        #pragma unroll
        for (int j = 0; j < 4; ++j)
            h[lq * 4 + j][c] = fmaxf(acc[nf][j] + bvv, 0.f);
    }
    __syncthreads();

    short8v a2[4];
    #pragma unroll
    for (int ks = 0; ks < 4; ++ks) {
        const float* hp = &h[lr][ks * 32 + lq * 8];
        a2[ks] = cvt8v(*(const float4*)hp, *(const float4*)(hp + 4));
    }
    float4v acc2[2];
    #pragma unroll
    for (int nf = 0; nf < 2; ++nf) acc2[nf] = (float4v){0.f, 0.f, 0.f, 0.f};
    #pragma unroll
    for (int ks = 0; ks < 4; ++ks) {
        #pragma unroll
        for (int nf = 0; nf < 2; ++nf) {
            short8v b = *(const short8v*)(WT2 + (w * 32 + nf * 16 + lr) * 128 + ks * 32 + lq * 8);
            acc2[nf] = mfma16(a2[ks], b, acc2[nf]);
        }
    }

    float s0 = 0.f, s1 = 0.f, s2 = 0.f, s3 = 0.f;
    #pragma unroll
    for (int nf = 0; nf < 2; ++nf) {
        const int c = w * 32 + nf * 16 + lr;
        const float w3v = W3[c];
        const float bvv = b2[c];
        s0 += fmaxf(acc2[nf][0] + bvv, 0.f) * w3v;
        s1 += fmaxf(acc2[nf][1] + bvv, 0.f) * w3v;
        s2 += fmaxf(acc2[nf][2] + bvv, 0.f) * w3v;
        s3 += fmaxf(acc2[nf][3] + bvv, 0.f) * w3v;
    }
    #pragma unroll
    for (int o = 1; o < 16; o <<= 1) {
        s0 += __shfl_xor(s0, o);
        s1 += __shfl_xor(s1, o);
        s2 += __shfl_xor(s2, o);
        s3 += __shfl_xor(s3, o);
    }
    if (lr == 0) {
        red[w][lq * 4 + 0] = s0;
        red[w][lq * 4 + 1] = s1;
        red[w][lq * 4 + 2] = s2;
        red[w][lq * 4 + 3] = s3;
    }
    __syncthreads();
    if (t < 16) out[p0 + t] = red[0][t] + red[1][t] + red[2][t] + red[3][t] + b3[0];
}

extern "C" void kernel_launch(void* const* d_in, const int* in_sizes, int n_in,
                              void* d_out, int out_size, void* d_ws, size_t ws_size,
                              hipStream_t stream)
{
    const float* feats[4] = {(const float*)d_in[0], (const float*)d_in[4], (const float*)d_in[8],  (const float*)d_in[12]};
    const int*   idxs[4]  = {(const int*)d_in[1],   (const int*)d_in[5],   (const int*)d_in[9],   (const int*)d_in[13]};
    const float* Ws[4]    = {(const float*)d_in[2], (const float*)d_in[6], (const float*)d_in[10], (const float*)d_in[14]};
    const float* bs[4]    = {(const float*)d_in[3], (const float*)d_in[7], (const float*)d_in[11], (const float*)d_in[15]};
    const float* gamma = (const float*)d_in[16];
    const float* beta  = (const float*)d_in[17];
    const float* W1 = (const float*)d_in[18]; const float* b1 = (const float*)d_in[19];
    const float* W2 = (const float*)d_in[20]; const float* b2 = (const float*)d_in[21];
    const float* W3 = (const float*)d_in[22]; const float* b3 = (const float*)d_in[23];
    int Ns[4] = {in_sizes[1], in_sizes[5], in_sizes[9], in_sizes[13]};

    // ws layout (bytes). Zero zone [0, 324352): counts|bnsum|done; x zeroed in-kernel
    char* ws = (char*)d_ws;
    int*   counts = (int*)(ws + 0);           //   320000
    float* bnsum  = (float*)(ws + 320000);    //     4096
    int*   done   = (int*)(ws + 324096);      //      256 (pad)
    float* x      = (float*)(ws + 324352);    // 40960000 -> 41284352
    int*   curs   = (int*)(ws + 41284352);    //   320000
    int* lists[4];
    lists[0] = (int*)(ws + 41604352);
    lists[1] = (int*)(ws + 42004992);
    lists[2] = (int*)(ws + 43605632);
    lists[3] = (int*)(ws + 43846272);         // -> 44166912
    int* splans[4];
    splans[0] = (int*)(ws + 44166912);
    splans[1] = (int*)(ws + 44567552);
    splans[2] = (int*)(ws + 46168192);
    splans[3] = (int*)(ws + 46408832);        // -> 46729472
    ushort* WTs[4];
    WTs[0] = (ushort*)(ws + 46729472);
    WTs[1] = (ushort*)(ws + 46754048);
    WTs[2] = (ushort*)(ws + 46795008);
    WTs[3] = (ushort*)(ws + 46811392);        // -> 46827776
    float* invc   = (float*)(ws + 46827776);  // -> 47147776
    ushort* WT1   = (ushort*)(ws + 47147776); // 131072
    ushort* WT2   = (ushort*)(ws + 47278848); // 32768 -> 47311616
    float* scale  = (float*)(ws + 47311616);
    float* shiftv = (float*)(ws + 47313664);

    // dispatch 1: small memset (counts + bnsum + done)
    hipMemsetAsync(ws, 0, 324352, stream);

    const int tot = Ns[0] + Ns[1] + Ns[2] + Ns[3];
    // dispatch 2: count + x-zero
    const int nb_count = (tot + 255) / 256;
    k_count_zero<<<nb_count + 2048, 256, 0, stream>>>(
        idxs[0], idxs[1], idxs[2], idxs[3], Ns[0], Ns[1], Ns[2], Ns[3], counts,
        nb_count, (float4*)x);
    // dispatch 3
    k_scan<<<4, 256, 0, stream>>>(counts, curs, invc,
        lists[0], lists[1], lists[2], lists[3],
        splans[0], splans[1], splans[2], splans[3],
        Ns[0], Ns[1], Ns[2], Ns[3]);
    // dispatch 4: fill + prepw
    const int nb_fill = (tot + 255) / 256;
    k_fill_prepw<<<nb_fill + 512, 256, 0, stream>>>(
        idxs[0], idxs[1], idxs[2], idxs[3], Ns[0], Ns[1], Ns[2], Ns[3], curs,
        lists[0], lists[1], lists[2], lists[3],
        splans[0], splans[1], splans[2], splans[3],
        nb_fill,
        Ws[0], Ws[1], Ws[2], Ws[3], W1, W2,
        WTs[0], WTs[1], WTs[2], WTs[3], WT1, WT2);
    // dispatch 5: encoder (128-row tiles, 512-thr blocks, pred first)
    const int ntp = (Ns[1] + 127) / 128, ntt = (Ns[0] + 127) / 128;
    const int nta = (Ns[2] + 127) / 128, ntj = (Ns[3] + 127) / 128;
    k_enc_all<<<ntp + ntt + nta + ntj, 512, 0, stream>>>(
        feats[0], feats[1], feats[2], feats[3],
        WTs[0], WTs[1], WTs[2], WTs[3],
        bs[0], bs[1], bs[2], bs[3],
        lists[0], lists[1], lists[2], lists[3],
        splans[0], splans[1], splans[2], splans[3],
        x, ntp, ntt, nta);
    // dispatch 6: BN stats + fused finalize
    k_bnstats<<<500, 512, 0, stream>>>(x, invc, bnsum, done, gamma, beta, scale, shiftv);
    // dispatch 7: head (16 rows/block)
    k_head<<<P_N / 16, 256, 0, stream>>>(x, invc, scale, shiftv,
                                         WT1, b1, WT2, b2, W3, b3, (float*)d_out);
}

// Round 17
// 368.094 us; speedup vs baseline: 1.0889x; 1.0889x over previous
//
#include <hip/hip_runtime.h>
#include <cstdint>

// MSCN forward, round 17: best-known config (R10/R15) + scan internals fix.
//  - k_scan: tree scan (was 256-iter serial on t==0); invc moved to fill blocks.
//  - enc: R10-exact (4 waves, 128-row tiles, (256,2)) - best measured 186us.
//  7 dispatches: memset(sm) | count+zero | scan | fill+prepw+invc | enc | bnstats | head

constexpr int P_N = 20000;
constexpr int HD  = 128;

typedef __attribute__((ext_vector_type(8))) short  short8v;
typedef __attribute__((ext_vector_type(4))) float  float4v;
typedef __attribute__((ext_vector_type(8))) float  float8v;
typedef __attribute__((ext_vector_type(8))) __bf16 bf16x8;

__device__ inline ushort f2bf(float f) {                       // RNE f32->bf16
    uint32_t u = __builtin_bit_cast(uint32_t, f);
    u += 0x7fffu + ((u >> 16) & 1u);
    return (ushort)(u >> 16);
}
__device__ inline short8v cvt8v(float4 a, float4 b) {          // v_cvt_pk_bf16
    float8v f = {a.x, a.y, a.z, a.w, b.x, b.y, b.z, b.w};
    bf16x8 h = __builtin_convertvector(f, bf16x8);
    return __builtin_bit_cast(short8v, h);
}
__device__ inline float4v mfma16(short8v a, short8v b, float4v c) {
    return __builtin_amdgcn_mfma_f32_16x16x32_bf16(a, b, c, 0, 0, 0);
}

// ---------------- histogram over all 4 types + x-zero fold ----------------
__global__ void k_count_zero(const int* __restrict__ i0, const int* __restrict__ i1,
                             const int* __restrict__ i2, const int* __restrict__ i3,
                             int n0, int n1, int n2, int n3, int* __restrict__ counts,
                             int nb_count, float4* __restrict__ xz) {
    if (blockIdx.x < (unsigned)nb_count) {
        int i = blockIdx.x * blockDim.x + threadIdx.x;
        const int n01 = n0 + n1, n012 = n0 + n1 + n2, tot = n012 + n3;
        if (i >= tot) return;
        int tp, li; const int* p;
        if (i < n0)        { tp = 0; li = i;        p = i0; }
        else if (i < n01)  { tp = 1; li = i - n0;   p = i1; }
        else if (i < n012) { tp = 2; li = i - n01;  p = i2; }
        else               { tp = 3; li = i - n012; p = i3; }
        atomicAdd(&counts[tp * P_N + p[li]], 1);
    } else {
        const int NZ = P_N * 128;
        int i = (blockIdx.x - nb_count) * blockDim.x + threadIdx.x;
        const int stride = 2048 * 256;
        const float4 z = {0.f, 0.f, 0.f, 0.f};
        for (; i < NZ; i += stride) xz[i] = z;
    }
}

// ---------------- scan (tree) -> curs + 160-entry list/splan pads ----------
__global__ void k_scan(int* __restrict__ counts_all, int* __restrict__ cur_all,
                       int* l0, int* l1, int* l2, int* l3,
                       int* s0, int* s1, int* s2, int* s3,
                       int n0, int n1, int n2, int n3) {
    const int type = blockIdx.x;
    int* counts = counts_all + type * P_N;
    int* curs   = cur_all   + type * P_N;
    const int T = 256;
    const int CH = (P_N + T - 1) / T;
    int t = threadIdx.x;
    __shared__ int sums[T];
    int local = 0;
    int p0 = t * CH;
    for (int i = 0; i < CH; ++i) {
        int p = p0 + i;
        if (p < P_N) local += counts[p];
    }
    sums[t] = local;
    __syncthreads();
    // Hillis-Steele inclusive scan over sums[256]
    #pragma unroll
    for (int o = 1; o < T; o <<= 1) {
        int u = (t >= o) ? sums[t - o] : 0;
        __syncthreads();
        sums[t] += u;
        __syncthreads();
    }
    int run = sums[t] - local;                 // exclusive prefix
    for (int i = 0; i < CH; ++i) {
        int p = p0 + i;
        if (p < P_N) { curs[p] = run; run += counts[p]; }
    }
    int N; int *lp, *sp;
    if (type == 0)      { N = n0; lp = l0; sp = s0; }
    else if (type == 1) { N = n1; lp = l1; sp = s1; }
    else if (type == 2) { N = n2; lp = l2; sp = s2; }
    else                { N = n3; lp = l3; sp = s3; }
    if (t < 160) { lp[N + t] = 0; sp[N + t] = -1; }
}

// ---------------- CSR fill + weight prep + invc, one dispatch --------------
__global__ void k_fill_prepw(const int* __restrict__ i0, const int* __restrict__ i1,
                             const int* __restrict__ i2, const int* __restrict__ i3,
                             int n0, int n1, int n2, int n3, int* __restrict__ cur_all,
                             int* l0, int* l1, int* l2, int* l3,
                             int* s0p, int* s1p, int* s2p, int* s3p,
                             int nb_fill,
                             const float* w0s, const float* w1s, const float* w2s,
                             const float* w3s, const float* w4s, const float* w5s,
                             ushort* d0, ushort* d1, ushort* d2, ushort* d3,
                             ushort* d4, ushort* d5,
                             const int* __restrict__ counts_all, float* __restrict__ invc) {
    if (blockIdx.x < (unsigned)nb_fill) {
        int i = blockIdx.x * blockDim.x + threadIdx.x;
        const int n01 = n0 + n1, n012 = n0 + n1 + n2, tot = n012 + n3;
        if (i >= tot) return;
        int tp, li; const int* p; int *lst, *spl;
        if (i < n0)        { tp = 0; li = i;        p = i0; lst = l0; spl = s0p; }
        else if (i < n01)  { tp = 1; li = i - n0;   p = i1; lst = l1; spl = s1p; }
        else if (i < n012) { tp = 2; li = i - n01;  p = i2; lst = l2; spl = s2p; }
        else               { tp = 3; li = i - n012; p = i3; lst = l3; spl = s3p; }
        int pl = p[li];
        int pos = atomicAdd(&cur_all[tp * P_N + pl], 1);
        lst[pos] = li;
        spl[pos] = pl;
    } else if (blockIdx.x < (unsigned)(nb_fill + 512)) {
        int i = (blockIdx.x - nb_fill) * blockDim.x + threadIdx.x;
        const float* s; ushort* d; int Dv, li;
        if (i < 12288)       { s = w0s; d = d0; Dv = 96;  li = i; }
        else if (i < 32768)  { s = w1s; d = d1; Dv = 160; li = i - 12288; }
        else if (i < 40960)  { s = w2s; d = d2; Dv = 64;  li = i - 32768; }
        else if (i < 49152)  { s = w3s; d = d3; Dv = 64;  li = i - 40960; }
        else if (i < 114688) { s = w4s; d = d4; Dv = 512; li = i - 49152; }
        else if (i < 131072) { s = w5s; d = d5; Dv = 128; li = i - 114688; }
        else return;
        int n = li / Dv, k = li - n * Dv;
        d[li] = f2bf(s[k * HD + n]);
    } else {
        int i = (blockIdx.x - nb_fill - 512) * blockDim.x + threadIdx.x;
        if (i < 4 * P_N) invc[i] = 1.f / (float)max(counts_all[i], 1);
    }
}

// ---------------- segment reduce over one 64-row group ----------------
__device__ __forceinline__ void reduce_group(float (*Cs)[132], const int* plans,
                                             float* __restrict__ x, int toff, int pbase) {
    const int t = threadIdx.x;
    const int col = t & 127, half = t >> 7;
    int curp = -2; float s = 0.f;
    #pragma unroll 8
    for (int r = 0; r < 32; ++r) {
        int p = plans[pbase + half * 32 + r];        // wave-uniform
        float v = Cs[half * 32 + r][col];
        if (p != curp) {
            if (curp >= 0) atomicAdd(&x[(size_t)curp * 512 + toff + col], s);
            s = 0.f; curp = p;
        }
        if (p >= 0) s += v;
    }
    if (curp >= 0) atomicAdd(&x[(size_t)curp * 512 + toff + col], s);
}

// ---------------- encoder body: one 128-row tile, 4 waves (R10-exact) ------
template<int D>
__device__ __forceinline__ void enc_body(
    const float* __restrict__ feat, const ushort* __restrict__ WT,
    const float* __restrict__ bias, const int* __restrict__ list,
    const int* __restrict__ splan, float* __restrict__ x, int toff, int tile,
    float (*Cs)[132], int* plans)
{
    constexpr int NKS = D / 32;
    const int t = threadIdx.x;
    const int w = t >> 6, lane = t & 63;
    const int lq = lane >> 4, lr = lane & 15;
    const int m0 = tile * 128;

    if (t < 128) plans[t] = splan[m0 + t];
    const int l0v = list[m0 + w * 16 + lr];
    const int l1v = list[m0 + 64 + w * 16 + lr];

    const float* a0p = feat + (size_t)l0v * D + lq * 8;
    const float* a1p = feat + (size_t)l1v * D + lq * 8;

    float4 s0[2 * NKS], s1[2 * NKS];
    #pragma unroll
    for (int ks = 0; ks < NKS; ++ks) {
        s0[2 * ks]     = *(const float4*)(a0p + ks * 32);
        s0[2 * ks + 1] = *(const float4*)(a0p + ks * 32 + 4);
    }
    #pragma unroll
    for (int ks = 0; ks < NKS; ++ks) {
        s1[2 * ks]     = *(const float4*)(a1p + ks * 32);
        s1[2 * ks + 1] = *(const float4*)(a1p + ks * 32 + 4);
    }
    short8v a0[NKS], a1[NKS];
    #pragma unroll
    for (int ks = 0; ks < NKS; ++ks) a0[ks] = cvt8v(s0[2 * ks], s0[2 * ks + 1]);
    #pragma unroll
    for (int ks = 0; ks < NKS; ++ks) a1[ks] = cvt8v(s1[2 * ks], s1[2 * ks + 1]);

    float bv[8];
    #pragma unroll
    for (int nf = 0; nf < 8; ++nf) bv[nf] = bias[nf * 16 + lr];

    float4v acc0[8], acc1[8];
    #pragma unroll
    for (int nf = 0; nf < 8; ++nf) {
        acc0[nf] = (float4v){0.f, 0.f, 0.f, 0.f};
        acc1[nf] = (float4v){0.f, 0.f, 0.f, 0.f};
    }

    const ushort* wp = WT + lr * D + lq * 8;
    short8v bcur[8];
    #pragma unroll
    for (int nf = 0; nf < 8; ++nf) bcur[nf] = *(const short8v*)(wp + nf * 16 * D);
    #pragma unroll
    for (int ks = 0; ks < NKS; ++ks) {
        short8v bnxt[8];
        if (ks + 1 < NKS) {
            #pragma unroll
            for (int nf = 0; nf < 8; ++nf)
                bnxt[nf] = *(const short8v*)(wp + nf * 16 * D + (ks + 1) * 32);
        }
        #pragma unroll
        for (int nf = 0; nf < 8; ++nf) acc0[nf] = mfma16(a0[ks], bcur[nf], acc0[nf]);
        #pragma unroll
        for (int nf = 0; nf < 8; ++nf) acc1[nf] = mfma16(a1[ks], bcur[nf], acc1[nf]);
        if (ks + 1 < NKS) {
            #pragma unroll
            for (int nf = 0; nf < 8; ++nf) bcur[nf] = bnxt[nf];
        }
    }

    #pragma unroll
    for (int nf = 0; nf < 8; ++nf) {
        #pragma unroll
        for (int j = 0; j < 4; ++j)
            Cs[w * 16 + lq * 4 + j][nf * 16 + lr] = fmaxf(acc0[nf][j] + bv[nf], 0.f);
    }
    __syncthreads();
    reduce_group(Cs, plans, x, toff, 0);
    __syncthreads();
    #pragma unroll
    for (int nf = 0; nf < 8; ++nf) {
        #pragma unroll
        for (int j = 0; j < 4; ++j)
            Cs[w * 16 + lq * 4 + j][nf * 16 + lr] = fmaxf(acc1[nf][j] + bv[nf], 0.f);
    }
    __syncthreads();
    reduce_group(Cs, plans, x, toff, 64);
}

__global__ __launch_bounds__(256, 2) void k_enc_all(
    const float* f0, const float* f1, const float* f2, const float* f3,
    const ushort* w0, const ushort* w1, const ushort* w2, const ushort* w3,
    const float* b0, const float* b1, const float* b2, const float* b3,
    const int* l0, const int* l1, const int* l2, const int* l3,
    const int* s0, const int* s1, const int* s2, const int* s3,
    float* x, int ntp, int ntt, int nta)
{
    __shared__ float Cs[64][132];
    __shared__ int plans[128];
    int bid = blockIdx.x;
    if (bid < ntp) { enc_body<160>(f1, w1, b1, l1, s1, x, 128, bid, Cs, plans); return; }
    bid -= ntp;
    if (bid < ntt) { enc_body<96>(f0, w0, b0, l0, s0, x, 0, bid, Cs, plans); return; }
    bid -= ntt;
    if (bid < nta) { enc_body<64>(f2, w2, b2, l2, s2, x, 256, bid, Cs, plans); return; }
    bid -= nta;
    enc_body<64>(f3, w3, b3, l3, s3, x, 384, bid, Cs, plans);
}

// ---------------- BN stats + fused finalize (last block) -------------------
__global__ __launch_bounds__(512) void k_bnstats(
    const float* __restrict__ x, const float* __restrict__ invc,
    float* __restrict__ bnsum, int* __restrict__ done,
    const float* __restrict__ gamma, const float* __restrict__ beta,
    float* __restrict__ scale, float* __restrict__ shiftv)
{
    const int t = threadIdx.x;
    const int r0 = blockIdx.x * 40;
    const int r1 = min(r0 + 40, P_N);
    const float* ic = invc + (t >> 7) * P_N;
    float s = 0.f, q = 0.f;
    for (int r = r0; r < r1; ++r) {
        float v = x[(size_t)r * 512 + t] * ic[r];
        s += v; q += v * v;
    }
    atomicAdd(&bnsum[t], s);
    atomicAdd(&bnsum[512 + t], q);

    __shared__ int amLast;
    __syncthreads();
    if (t == 0) {
        __threadfence();
        int prev = __hip_atomic_fetch_add(done, 1, __ATOMIC_ACQ_REL, __HIP_MEMORY_SCOPE_AGENT);
        amLast = (prev == (int)gridDim.x - 1);
    }
    __syncthreads();
    if (amLast) {
        const float invn = 1.f / (float)P_N;
        float sm = __hip_atomic_load(&bnsum[t],       __ATOMIC_RELAXED, __HIP_MEMORY_SCOPE_AGENT);
        float sq = __hip_atomic_load(&bnsum[512 + t], __ATOMIC_RELAXED, __HIP_MEMORY_SCOPE_AGENT);
        float mu  = sm * invn;
        float var = sq * invn - mu * mu;
        float rstd = rsqrtf(fmaxf(var, 0.f) + 1e-5f);
        float sc = gamma[t] * rstd;
        scale[t]  = sc;
        shiftv[t] = beta[t] - mu * sc;
    }
}

// ---------------- fused MFMA head: 16 plans/block, 1250 blocks -------------
__global__ __launch_bounds__(256) void k_head(
    const float* __restrict__ x, const float* __restrict__ invc,
    const float* __restrict__ scale, const float* __restrict__ shiftv,
    const ushort* __restrict__ WT1, const float* __restrict__ b1,
    const ushort* __restrict__ WT2, const float* __restrict__ b2,
    const float* __restrict__ W3, const float* __restrict__ b3,
    float* __restrict__ out)
{
    __shared__ float h[16][132];
    __shared__ float red[4][16];
    const int t = threadIdx.x;
    const int w = t >> 6, lane = t & 63;
    const int lq = lane >> 4, lr = lane & 15;
    const int p0 = blockIdx.x * 16;
    const int row = p0 + lr;
    const float* xr = x + (size_t)row * 512;

    float4v acc[2];
    #pragma unroll
    for (int nf = 0; nf < 2; ++nf) acc[nf] = (float4v){0.f, 0.f, 0.f, 0.f};

    #pragma unroll
    for (int kc = 0; kc < 4; ++kc) {
        const float ic = invc[kc * P_N + row];
        float4 st[8];
        #pragma unroll
        for (int k2 = 0; k2 < 4; ++k2) {
            const int k0 = kc * 128 + k2 * 32 + lq * 8;
            st[2 * k2]     = *(const float4*)(xr + k0);
            st[2 * k2 + 1] = *(const float4*)(xr + k0 + 4);
        }
        short8v a[4];
        #pragma unroll
        for (int k2 = 0; k2 < 4; ++k2) {
            const int k0 = kc * 128 + k2 * 32 + lq * 8;
            float4 sc0 = *(const float4*)(scale + k0);
            float4 sc1 = *(const float4*)(scale + k0 + 4);
            float4 sh0 = *(const float4*)(shiftv + k0);
            float4 sh1 = *(const float4*)(shiftv + k0 + 4);
            float4 v0, v1;
            v0.x = st[2*k2].x   * ic * sc0.x + sh0.x;
            v0.y = st[2*k2].y   * ic * sc0.y + sh0.y;
            v0.z = st[2*k2].z   * ic * sc0.z + sh0.z;
            v0.w = st[2*k2].w   * ic * sc0.w + sh0.w;
            v1.x = st[2*k2+1].x * ic * sc1.x + sh1.x;
            v1.y = st[2*k2+1].y * ic * sc1.y + sh1.y;
            v1.z = st[2*k2+1].z * ic * sc1.z + sh1.z;
            v1.w = st[2*k2+1].w * ic * sc1.w + sh1.w;
            a[k2] = cvt8v(v0, v1);
        }
        #pragma unroll
        for (int k2 = 0; k2 < 4; ++k2) {
            const int ks = kc * 4 + k2;
            #pragma unroll
            for (int nf = 0; nf < 2; ++nf) {
                short8v b = *(const short8v*)(WT1 + (size_t)(w * 32 + nf * 16 + lr) * 512 + ks * 32 + lq * 8);
                acc[nf] = mfma16(a[k2], b, acc[nf]);
            }
        }
    }
    #pragma unroll
    for (int nf = 0; nf < 2; ++nf) {
        const int c = w * 32 + nf * 16 + lr;
        const float bvv = b1[c];
        #pragma unroll
        for (int j = 0; j < 4; ++j)
            h[lq * 4 + j][c] = fmaxf(acc[nf][j] + bvv, 0.f);
    }
    __syncthreads();

    short8v a2[4];
    #pragma unroll
    for (int ks = 0; ks < 4; ++ks) {
        const float* hp = &h[lr][ks * 32 + lq * 8];
        a2[ks] = cvt8v(*(const float4*)hp, *(const float4*)(hp + 4));
    }
    float4v acc2[2];
    #pragma unroll
    for (int nf = 0; nf < 2; ++nf) acc2[nf] = (float4v){0.f, 0.f, 0.f, 0.f};
    #pragma unroll
    for (int ks = 0; ks < 4; ++ks) {
        #pragma unroll
        for (int nf = 0; nf < 2; ++nf) {
            short8v b = *(const short8v*)(WT2 + (w * 32 + nf * 16 + lr) * 128 + ks * 32 + lq * 8);
            acc2[nf] = mfma16(a2[ks], b, acc2[nf]);
        }
    }

    float s0 = 0.f, s1 = 0.f, s2 = 0.f, s3 = 0.f;
    #pragma unroll
    for (int nf = 0; nf < 2; ++nf) {
        const int c = w * 32 + nf * 16 + lr;
        const float w3v = W3[c];
        const float bvv = b2[c];
        s0 += fmaxf(acc2[nf][0] + bvv, 0.f) * w3v;
        s1 += fmaxf(acc2[nf][1] + bvv, 0.f) * w3v;
        s2 += fmaxf(acc2[nf][2] + bvv, 0.f) * w3v;
        s3 += fmaxf(acc2[nf][3] + bvv, 0.f) * w3v;
    }
    #pragma unroll
    for (int o = 1; o < 16; o <<= 1) {
        s0 += __shfl_xor(s0, o);
        s1 += __shfl_xor(s1, o);
        s2 += __shfl_xor(s2, o);
        s3 += __shfl_xor(s3, o);
    }
    if (lr == 0) {
        red[w][lq * 4 + 0] = s0;
        red[w][lq * 4 + 1] = s1;
        red[w][lq * 4 + 2] = s2;
        red[w][lq * 4 + 3] = s3;
    }
    __syncthreads();
    if (t < 16) out[p0 + t] = red[0][t] + red[1][t] + red[2][t] + red[3][t] + b3[0];
}

extern "C" void kernel_launch(void* const* d_in, const int* in_sizes, int n_in,
                              void* d_out, int out_size, void* d_ws, size_t ws_size,
                              hipStream_t stream)
{
    const float* feats[4] = {(const float*)d_in[0], (const float*)d_in[4], (const float*)d_in[8],  (const float*)d_in[12]};
    const int*   idxs[4]  = {(const int*)d_in[1],   (const int*)d_in[5],   (const int*)d_in[9],   (const int*)d_in[13]};
    const float* Ws[4]    = {(const float*)d_in[2], (const float*)d_in[6], (const float*)d_in[10], (const float*)d_in[14]};
    const float* bs[4]    = {(const float*)d_in[3], (const float*)d_in[7], (const float*)d_in[11], (const float*)d_in[15]};
    const float* gamma = (const float*)d_in[16];
    const float* beta  = (const float*)d_in[17];
    const float* W1 = (const float*)d_in[18]; const float* b1 = (const float*)d_in[19];
    const float* W2 = (const float*)d_in[20]; const float* b2 = (const float*)d_in[21];
    const float* W3 = (const float*)d_in[22]; const float* b3 = (const float*)d_in[23];
    int Ns[4] = {in_sizes[1], in_sizes[5], in_sizes[9], in_sizes[13]};

    // ws layout (bytes). Zero zone [0, 324352): counts|bnsum|done; x zeroed in-kernel
    char* ws = (char*)d_ws;
    int*   counts = (int*)(ws + 0);           //   320000
    float* bnsum  = (float*)(ws + 320000);    //     4096
    int*   done   = (int*)(ws + 324096);      //      256 (pad)
    float* x      = (float*)(ws + 324352);    // 40960000 -> 41284352
    int*   curs   = (int*)(ws + 41284352);    //   320000
    int* lists[4];
    lists[0] = (int*)(ws + 41604352);
    lists[1] = (int*)(ws + 42004992);
    lists[2] = (int*)(ws + 43605632);
    lists[3] = (int*)(ws + 43846272);         // -> 44166912
    int* splans[4];
    splans[0] = (int*)(ws + 44166912);
    splans[1] = (int*)(ws + 44567552);
    splans[2] = (int*)(ws + 46168192);
    splans[3] = (int*)(ws + 46408832);        // -> 46729472
    ushort* WTs[4];
    WTs[0] = (ushort*)(ws + 46729472);
    WTs[1] = (ushort*)(ws + 46754048);
    WTs[2] = (ushort*)(ws + 46795008);
    WTs[3] = (ushort*)(ws + 46811392);        // -> 46827776
    float* invc   = (float*)(ws + 46827776);  // -> 47147776
    ushort* WT1   = (ushort*)(ws + 47147776); // 131072
    ushort* WT2   = (ushort*)(ws + 47278848); // 32768 -> 47311616
    float* scale  = (float*)(ws + 47311616);
    float* shiftv = (float*)(ws + 47313664);

    // dispatch 1: small memset (counts + bnsum + done)
    hipMemsetAsync(ws, 0, 324352, stream);

    const int tot = Ns[0] + Ns[1] + Ns[2] + Ns[3];
    // dispatch 2: count + x-zero
    const int nb_count = (tot + 255) / 256;
    k_count_zero<<<nb_count + 2048, 256, 0, stream>>>(
        idxs[0], idxs[1], idxs[2], idxs[3], Ns[0], Ns[1], Ns[2], Ns[3], counts,
        nb_count, (float4*)x);
    // dispatch 3: tree scan
    k_scan<<<4, 256, 0, stream>>>(counts, curs,
        lists[0], lists[1], lists[2], lists[3],
        splans[0], splans[1], splans[2], splans[3],
        Ns[0], Ns[1], Ns[2], Ns[3]);
    // dispatch 4: fill + prepw + invc
    const int nb_fill = (tot + 255) / 256;
    const int nb_invc = (4 * P_N + 255) / 256;
    k_fill_prepw<<<nb_fill + 512 + nb_invc, 256, 0, stream>>>(
        idxs[0], idxs[1], idxs[2], idxs[3], Ns[0], Ns[1], Ns[2], Ns[3], curs,
        lists[0], lists[1], lists[2], lists[3],
        splans[0], splans[1], splans[2], splans[3],
        nb_fill,
        Ws[0], Ws[1], Ws[2], Ws[3], W1, W2,
        WTs[0], WTs[1], WTs[2], WTs[3], WT1, WT2,
        counts, invc);
    // dispatch 5: encoder (R10-exact: 128-row tiles, 4 waves, pred first)
    const int ntp = (Ns[1] + 127) / 128, ntt = (Ns[0] + 127) / 128;
    const int nta = (Ns[2] + 127) / 128, ntj = (Ns[3] + 127) / 128;
    k_enc_all<<<ntp + ntt + nta + ntj, 256, 0, stream>>>(
        feats[0], feats[1], feats[2], feats[3],
        WTs[0], WTs[1], WTs[2], WTs[3],
        bs[0], bs[1], bs[2], bs[3],
        lists[0], lists[1], lists[2], lists[3],
        splans[0], splans[1], splans[2], splans[3],
        x, ntp, ntt, nta);
    // dispatch 6: BN stats + fused finalize
    k_bnstats<<<500, 512, 0, stream>>>(x, invc, bnsum, done, gamma, beta, scale, shiftv);
    // dispatch 7: head (16 rows/block)
    k_head<<<P_N / 16, 256, 0, stream>>>(x, invc, scale, shiftv,
                                         WT1, b1, WT2, b2, W3, b3, (float*)d_out);
}